// Round 1
// baseline (411.060 us; speedup 1.0000x reference)
//
#include <hip/hip_runtime.h>
#include <stdint.h>

typedef __attribute__((ext_vector_type(8))) short short8;
typedef __attribute__((ext_vector_type(4))) float f32x4;

// ---- workspace (bf16 transposed weights) segment offsets, in shorts ----
#define OW1R  0        // [64][64]    rad_w1^T
#define OW2R  4096     // [768][64]   rad_w2^T
#define OW0T  53248    // [384][384]  lin_w0^T * INV_SQRT_FAN
#define OW1CT 200704   // [128][256]  lin_w1[:256]^T * INV_SQRT_FAN
#define OW1DT 233472   // [128][128]  lin_w1[256:]^T * INV_SQRT_FAN
#define WS_SHORTS 249856

// ---- LDS layout (bytes) ----
#define OATTR 0        // [32][4] f32 edge_attr
#define OES   512      // [32][64] bf16, swizzled (A for G1)
#define OHS   4608     // [32][64] bf16, swizzled (A for G2)
#define OD0   8704     // [32][384] bf16, swizzled (A for out0 GEMM)
#define OH    8704     // [32][68] f32 (LN staging; overlaps OD0, dead before d0 written)
#define OZC   33280    // [32][256] bf16, swizzled
#define OZD0  49664    // [32][128] bf16, swizzled
#define OZD1  57856
#define OZD2  66048
#define SMEM_BYTES 74240

static constexpr float C_SILU      = 1.6765390f;   // 1/sqrt(E[silu(z)^2])
static constexpr float C_SIG       = 1.8462240f;   // 1/sqrt(E[sigmoid(z)^2])
static constexpr float INV_SQRT3   = 0.5773502691896258f;
static constexpr float INV_SQRT2   = 0.7071067811865476f;
static constexpr float INV_SQRT_FAN= 0.051031036307982884f; // 1/sqrt(384)

__device__ __forceinline__ short f2bf(float f) {
  union { float f; uint32_t u; } v; v.f = f;
  uint32_t u = v.u;
  u += 0x7FFFu + ((u >> 16) & 1u);   // RNE to bf16
  return (short)(u >> 16);
}

__device__ __forceinline__ f32x4 mfma16(short8 a, short8 b, f32x4 c) {
  return __builtin_amdgcn_mfma_f32_16x16x32_bf16(a, b, c, 0, 0, 0);
}

// B fragment from global bf16 weight stored [N][K] row-major.
__device__ __forceinline__ short8 ldB(const short* __restrict__ W, int K, int nt, int kt, int lane) {
  int n  = (nt << 4) + (lane & 15);
  int k0 = (kt << 5) + ((lane >> 4) << 3);
  return *(const short8*)(W + n * K + k0);
}

// ---------- weight prep: transpose + bf16 convert (+scale fold) ----------
__global__ void prep_weights(const float* __restrict__ rw1, const float* __restrict__ rw2,
                             const float* __restrict__ lw0, const float* __restrict__ lw1,
                             short* __restrict__ ws)
{
  int idx = blockIdx.x * blockDim.x + threadIdx.x;
  int stride = gridDim.x * blockDim.x;
  for (int i = idx; i < 64 * 64; i += stride) {
    int n = i >> 6, k = i & 63;
    ws[OW1R + i] = f2bf(rw1[k * 64 + n]);
  }
  for (int i = idx; i < 768 * 64; i += stride) {
    int n = i >> 6, k = i & 63;
    ws[OW2R + i] = f2bf(rw2[k * 768 + n]);
  }
  for (int i = idx; i < 384 * 384; i += stride) {
    int n = i / 384, k = i - n * 384;
    ws[OW0T + i] = f2bf(lw0[k * 384 + n] * INV_SQRT_FAN);
  }
  for (int i = idx; i < 128 * 256; i += stride) {
    int v = i >> 8, u = i & 255;
    ws[OW1CT + i] = f2bf(lw1[u * 128 + v] * INV_SQRT_FAN);
  }
  for (int i = idx; i < 128 * 128; i += stride) {
    int v = i >> 7, u = i & 127;
    ws[OW1DT + i] = f2bf(lw1[(256 + u) * 128 + v] * INV_SQRT_FAN);
  }
}

// ---------- fused main kernel: 32 edges per block ----------
__global__ __launch_bounds__(256) void fctp_fused(
    const float* __restrict__ node, const float* __restrict__ eattr,
    const float* __restrict__ escal, const float* __restrict__ lng,
    const float* __restrict__ lnb, const float* __restrict__ roff,
    const float* __restrict__ b0v, const short* __restrict__ ws,
    float* __restrict__ out)
{
  __shared__ char smem[SMEM_BYTES];
  const int t = threadIdx.x;
  const int lane = t & 63;
  const int w = t >> 6;
  const int row0 = blockIdx.x << 5;

// swizzled bf16 tile accessors (row stride c2 bytes, multiple of 128)
#define LDA(base, c2, row, k0) \
  (*(const short8*)(smem + (base) + (row) * (c2) + ((((k0) << 1)) ^ (((row) & 7) << 4))))
#define STBF(base, c2, row, col, val) \
  (*(short*)(smem + (base) + (row) * (c2) + ((((col) << 1)) ^ (((row) & 7) << 4))) = f2bf(val))

  // ---- phase 0: stage edge_attr (f32) and edge_scalars (bf16 swizzled) ----
  {
    if (t < 128) {
      ((float*)(smem + OATTR))[t] = eattr[(size_t)row0 * 4 + t];
    }
    int r = t >> 3, c0 = (t & 7) << 3;
    const float* p = escal + (size_t)(row0 + r) * 64 + c0;
    float4 v0 = *(const float4*)p;
    float4 v1 = *(const float4*)(p + 4);
    short8 bv;
    bv[0] = f2bf(v0.x); bv[1] = f2bf(v0.y); bv[2] = f2bf(v0.z); bv[3] = f2bf(v0.w);
    bv[4] = f2bf(v1.x); bv[5] = f2bf(v1.y); bv[6] = f2bf(v1.z); bv[7] = f2bf(v1.w);
    *(short8*)(smem + OES + r * 128 + ((c0 << 1) ^ ((r & 7) << 4))) = bv;
  }
  __syncthreads();

  // ---- phase 1: h = es @ rad_w1  (G1), write f32 h to LDS ----
  {
    short8 bf0 = ldB(ws + OW1R, 64, w, 0, lane);
    short8 bf1 = ldB(ws + OW1R, 64, w, 1, lane);
    float* sh_h = (float*)(smem + OH);
    int colh = (w << 4) + (lane & 15);
    int kof = (lane >> 4) << 3;
#pragma unroll
    for (int rt = 0; rt < 2; ++rt) {
      int r = rt * 16 + (lane & 15);
      f32x4 acc = {0.f, 0.f, 0.f, 0.f};
      acc = mfma16(LDA(OES, 128, r, kof), bf0, acc);
      acc = mfma16(LDA(OES, 128, r, 32 + kof), bf1, acc);
      int rb = rt * 16 + ((lane >> 4) << 2);
#pragma unroll
      for (int i = 0; i < 4; ++i) sh_h[(rb + i) * 68 + colh] = acc[i];
    }
  }
  __syncthreads();

  // ---- phase 2: LayerNorm + silu -> HS (bf16 swizzled) ----
  {
    const float* sh_h = (const float*)(smem + OH);
    int r = t >> 3, g8 = t & 7;
    float vals[8]; float s = 0.f, s2 = 0.f;
#pragma unroll
    for (int j = 0; j < 8; ++j) {
      float v = sh_h[r * 68 + g8 * 8 + j];
      vals[j] = v; s += v; s2 += v * v;
    }
#pragma unroll
    for (int off = 1; off < 8; off <<= 1) {
      s  += __shfl_xor(s, off, 64);
      s2 += __shfl_xor(s2, off, 64);
    }
    float mu = s * 0.015625f;
    float var = s2 * 0.015625f - mu * mu;
    float rstd = rsqrtf(var + 1e-5f);
    short8 hv;
#pragma unroll
    for (int j = 0; j < 8; ++j) {
      int c = g8 * 8 + j;
      float v = (vals[j] - mu) * rstd * lng[c] + lnb[c];
      float sv = v / (1.f + __expf(-v));
      hv[j] = f2bf(sv);
    }
    *(short8*)(smem + OHS + r * 128 + (((g8 * 8) << 1) ^ ((r & 7) << 4))) = hv;
  }
  __syncthreads();

  // ---- phase 3: w = hs @ rad_w2 (+offset) fused into d0 / zC / zD builds ----
  {
    const float* attr = (const float*)(smem + OATTR);
    int kof = (lane >> 4) << 3;
    short8 a00 = LDA(OHS, 128, (lane & 15), kof);
    short8 a01 = LDA(OHS, 128, (lane & 15), 32 + kof);
    short8 a10 = LDA(OHS, 128, 16 + (lane & 15), kof);
    short8 a11 = LDA(OHS, 128, 16 + (lane & 15), 32 + kof);

    // wA (cols 0..255) paired with wC (256..511): share x0 reads
#pragma unroll
    for (int j = 0; j < 4; ++j) {
      int ut = (w << 2) + j;
      short8 bA0 = ldB(ws + OW2R, 64, ut, 0, lane);
      short8 bA1 = ldB(ws + OW2R, 64, ut, 1, lane);
      short8 bC0 = ldB(ws + OW2R, 64, ut + 16, 0, lane);
      short8 bC1 = ldB(ws + OW2R, 64, ut + 16, 1, lane);
      int u = (ut << 4) + (lane & 15);
      float offA = roff[u], offC = roff[256 + u];
#pragma unroll
      for (int rt = 0; rt < 2; ++rt) {
        short8 fa = rt ? a10 : a00, fb = rt ? a11 : a01;
        f32x4 accA = {0.f,0.f,0.f,0.f}, accC = {0.f,0.f,0.f,0.f};
        accA = mfma16(fa, bA0, accA); accA = mfma16(fb, bA1, accA);
        accC = mfma16(fa, bC0, accC); accC = mfma16(fb, bC1, accC);
        int rb = rt * 16 + ((lane >> 4) << 2);
#pragma unroll
        for (int i = 0; i < 4; ++i) {
          int row = rb + i;
          float x0v = node[(size_t)(row0 + row) * 640 + u];
          float s0 = attr[row * 4 + 0];
          STBF(OD0, 768, row, u, x0v * s0 * (accA[i] + offA));
          STBF(OZC, 512, row, u, x0v * (accC[i] + offC));
        }
      }
    }
    // wB (512..639) paired with wD (640..767): share x1 reads
#pragma unroll
    for (int j = 0; j < 2; ++j) {
      int ut = (w << 1) + j;
      short8 bB0 = ldB(ws + OW2R, 64, 32 + ut, 0, lane);
      short8 bB1 = ldB(ws + OW2R, 64, 32 + ut, 1, lane);
      short8 bD0 = ldB(ws + OW2R, 64, 40 + ut, 0, lane);
      short8 bD1 = ldB(ws + OW2R, 64, 40 + ut, 1, lane);
      int u = (ut << 4) + (lane & 15);
      float offB = roff[512 + u], offD = roff[640 + u];
#pragma unroll
      for (int rt = 0; rt < 2; ++rt) {
        short8 fa = rt ? a10 : a00, fb = rt ? a11 : a01;
        f32x4 accB = {0.f,0.f,0.f,0.f}, accD = {0.f,0.f,0.f,0.f};
        accB = mfma16(fa, bB0, accB); accB = mfma16(fb, bB1, accB);
        accD = mfma16(fa, bD0, accD); accD = mfma16(fb, bD1, accD);
        int rb = rt * 16 + ((lane >> 4) << 2);
#pragma unroll
        for (int i = 0; i < 4; ++i) {
          int row = rb + i;
          const float* xp = node + (size_t)(row0 + row) * 640 + 256 + u * 3;
          float xa = xp[0], xb = xp[1], xc = xp[2];
          float sa = attr[row * 4 + 1], sb = attr[row * 4 + 2], sc = attr[row * 4 + 3];
          float wB = accB[i] + offB, wD = accD[i] + offD;
          STBF(OD0, 768, row, 256 + u, (xa * sa + xb * sb + xc * sc) * INV_SQRT3 * wB);
          float zd = wD * INV_SQRT2;
          STBF(OZD0, 256, row, u, xa * zd);
          STBF(OZD1, 256, row, u, xb * zd);
          STBF(OZD2, 256, row, u, xc * zd);
        }
      }
    }
  }
  __syncthreads();

  // ---- phase 4a: out0 scalar half (cols 0..255) -> silu -> out ----
  {
    int kof = (lane >> 4) << 3;
#pragma unroll
    for (int j = 0; j < 4; ++j) {
      int nt = (w << 2) + j;
      int col = (nt << 4) + (lane & 15);
      float bias = b0v[col];
      f32x4 acc0 = {0.f,0.f,0.f,0.f}, acc1 = {0.f,0.f,0.f,0.f};
      for (int kt = 0; kt < 12; ++kt) {
        short8 bf = ldB(ws + OW0T, 384, nt, kt, lane);
        int k0 = (kt << 5) + kof;
        acc0 = mfma16(LDA(OD0, 768, (lane & 15), k0), bf, acc0);
        acc1 = mfma16(LDA(OD0, 768, 16 + (lane & 15), k0), bf, acc1);
      }
#pragma unroll
      for (int rt = 0; rt < 2; ++rt) {
        f32x4 acc = rt ? acc1 : acc0;
        int rb = rt * 16 + ((lane >> 4) << 2);
#pragma unroll
        for (int i = 0; i < 4; ++i) {
          float v = acc[i] + bias;
          float sv = v / (1.f + __expf(-v));
          out[(size_t)(row0 + rb + i) * 640 + col] = C_SILU * sv;
        }
      }
    }
  }

  // ---- phase 4b: gates + factored out1 -> gated outputs ----
  {
    const float* attr = (const float*)(smem + OATTR);
    int kof = (lane >> 4) << 3;
#pragma unroll
    for (int j = 0; j < 2; ++j) {
      int vt = (w << 1) + j;
      int v = (vt << 4) + (lane & 15);
      float bias = b0v[256 + v];
      f32x4 g0={0.f,0.f,0.f,0.f}, g1={0.f,0.f,0.f,0.f};
      f32x4 yc0={0.f,0.f,0.f,0.f}, yc1={0.f,0.f,0.f,0.f};
      f32x4 p00={0.f,0.f,0.f,0.f}, p01={0.f,0.f,0.f,0.f};
      f32x4 p10={0.f,0.f,0.f,0.f}, p11={0.f,0.f,0.f,0.f};
      f32x4 p20={0.f,0.f,0.f,0.f}, p21={0.f,0.f,0.f,0.f};
      for (int kt = 0; kt < 12; ++kt) {
        short8 bf = ldB(ws + OW0T, 384, 16 + vt, kt, lane);
        int k0 = (kt << 5) + kof;
        g0 = mfma16(LDA(OD0, 768, (lane & 15), k0), bf, g0);
        g1 = mfma16(LDA(OD0, 768, 16 + (lane & 15), k0), bf, g1);
      }
      for (int kt = 0; kt < 8; ++kt) {
        short8 bf = ldB(ws + OW1CT, 256, vt, kt, lane);
        int k0 = (kt << 5) + kof;
        yc0 = mfma16(LDA(OZC, 512, (lane & 15), k0), bf, yc0);
        yc1 = mfma16(LDA(OZC, 512, 16 + (lane & 15), k0), bf, yc1);
      }
      for (int kt = 0; kt < 4; ++kt) {
        short8 bf = ldB(ws + OW1DT, 128, vt, kt, lane);
        int k0 = (kt << 5) + kof;
        p00 = mfma16(LDA(OZD0, 256, (lane & 15), k0), bf, p00);
        p01 = mfma16(LDA(OZD0, 256, 16 + (lane & 15), k0), bf, p01);
        p10 = mfma16(LDA(OZD1, 256, (lane & 15), k0), bf, p10);
        p11 = mfma16(LDA(OZD1, 256, 16 + (lane & 15), k0), bf, p11);
        p20 = mfma16(LDA(OZD2, 256, (lane & 15), k0), bf, p20);
        p21 = mfma16(LDA(OZD2, 256, 16 + (lane & 15), k0), bf, p21);
      }
#pragma unroll
      for (int rt = 0; rt < 2; ++rt) {
        f32x4 gg = rt ? g1 : g0;
        f32x4 yc = rt ? yc1 : yc0;
        f32x4 q0 = rt ? p01 : p00;
        f32x4 q1 = rt ? p11 : p10;
        f32x4 q2 = rt ? p21 : p20;
        int rb = rt * 16 + ((lane >> 4) << 2);
#pragma unroll
        for (int i = 0; i < 4; ++i) {
          int row = rb + i;
          float gate = C_SIG / (1.f + __expf(-(gg[i] + bias)));
          float sa = attr[row * 4 + 1], sb = attr[row * 4 + 2], sc = attr[row * 4 + 3];
          float o0 = sa * yc[i] + (sc * q1[i] - sb * q2[i]);
          float o1 = sb * yc[i] + (sa * q2[i] - sc * q0[i]);
          float o2 = sc * yc[i] + (sb * q0[i] - sa * q1[i]);
          float* op = out + (size_t)(row0 + row) * 640 + 256 + v * 3;
          op[0] = o0 * gate; op[1] = o1 * gate; op[2] = o2 * gate;
        }
      }
    }
  }
#undef LDA
#undef STBF
}

extern "C" void kernel_launch(void* const* d_in, const int* in_sizes, int n_in,
                              void* d_out, int out_size, void* d_ws, size_t ws_size,
                              hipStream_t stream) {
  const float* node_input   = (const float*)d_in[0];
  const float* edge_attr    = (const float*)d_in[1];
  const float* edge_scalars = (const float*)d_in[2];
  const float* rad_w1       = (const float*)d_in[3];
  const float* rad_ln_g     = (const float*)d_in[4];
  const float* rad_ln_b     = (const float*)d_in[5];
  const float* rad_w2       = (const float*)d_in[6];
  const float* rad_offset   = (const float*)d_in[7];
  const float* lin_w0       = (const float*)d_in[8];
  const float* lin_b0       = (const float*)d_in[9];
  const float* lin_w1       = (const float*)d_in[10];
  short* wsb = (short*)d_ws;
  float* out = (float*)d_out;

  prep_weights<<<256, 256, 0, stream>>>(rad_w1, rad_w2, lin_w0, lin_w1, wsb);
  fctp_fused<<<131072 / 32, 256, 0, stream>>>(node_input, edge_attr, edge_scalars,
                                              rad_ln_g, rad_ln_b, rad_offset,
                                              lin_b0, wsb, out);
}